// Round 8
// baseline (111.520 us; speedup 1.0000x reference)
//
#include <hip/hip_runtime.h>
#include <hip/hip_fp16.h>

// Problem constants (must match reference)
#define NUM_PHYSICAL 2000000
#define NUM_NODES    2500000   // 2,000,000 physical + 500,000 filler
#define NBX 512
#define NBY 512
#define NBINS (NBX * NBY)

// BSX = BSY = 1000/512 = 1.953125 (exact in binary)
#define BSX 1.953125f
#define HALF_STRETCH ((float)(0.5 * 1.953125 * 1.4142135623730951))
// BSX*BSY*UNIT_PIN_CAPACITY = 61.03515625 (exact)
#define NORM_DIV 61.03515625f
#define MAX_RATE 2.5f
#define MIN_RATE 0.4f   // 1/2.5 exactly

// Bucketing: 64 y-strips x 4 footprint shapes (spanx,spany in {2,3}).
#define NSTRIP 64
#define NSHAPE 4
#define NBUCK (NSTRIP * NSHAPE)   // 256
#define SROWS 8                   // rows per strip
#define LROWS (SROWS + 2)         // +2 y-halo (node spans <=3 rows)
#define SCELLS (LROWS * NBX)      // 5120 floats = 20 KB LDS
#define RREP 8                    // scatter replicas per strip
#define SCAT_BLOCKS (NSTRIP * RREP)
#define SCAT_THREADS 1024
#define HB 1024                   // blocks for hist/placement
#define CHUNK ((NUM_PHYSICAL + HB - 1) / HB)   // 1954

__device__ __forceinline__ void node_box(const float* __restrict__ pos,
                                         const float* __restrict__ nsx,
                                         const float* __restrict__ nsy, int i,
                                         float& x_min, float& y_min,
                                         float& hx, float& hy) {
    float sx = nsx[i], sy = nsy[i];
    hx = 0.5f * fmaxf(sx, 2.0f * HALF_STRETCH);
    hy = 0.5f * fmaxf(sy, 2.0f * HALF_STRETCH);
    x_min = (pos[i]             + 0.5f * sx) - hx;
    y_min = (pos[NUM_NODES + i] + 0.5f * sy) - hy;
}

__device__ __forceinline__ float pack_hxy(float hx, float hy) {
    unsigned int u = ((unsigned int)__half_as_ushort(__float2half_rn(hy)) << 16)
                   |  (unsigned int)__half_as_ushort(__float2half_rn(hx));
    return __uint_as_float(u);
}
__device__ __forceinline__ void unpack_hxy(float p, float& hx, float& hy) {
    unsigned int u = __float_as_uint(p);
    hx = __half2float(__ushort_as_half((unsigned short)(u & 0xffffu)));
    hy = __half2float(__ushort_as_half((unsigned short)(u >> 16)));
}

// Bucket = strip*4 + shx*2 + shy, spans derived from the f16-reconstructed
// box — MUST be recomputed identically in hist and place, and the scatter
// kernel trusts the segment's shape (it recomputes the same x_max/y_max from
// the payload's f16 fields, so the spans match bit-exactly).
__device__ __forceinline__ int bucket_of(float x_min, float y_min,
                                         float hx, float hy) {
    float hx16 = __half2float(__float2half_rn(hx));
    float hy16 = __half2float(__float2half_rn(hy));
    float x_max = x_min + 2.0f * hx16;
    float y_max = y_min + 2.0f * hy16;
    int bxl = (int)floorf(x_min / BSX);
    int byl = (int)floorf(y_min / BSX);
    int strip = (min(max(byl, 0), NBY - 1)) >> 3;
    int shx = ((int)floorf(x_max / BSX) - bxl >= 2) ? 1 : 0;
    int shy = ((int)floorf(y_max / BSX) - byl >= 2) ? 1 : 0;
    return strip * NSHAPE + shx * 2 + shy;
}

// ---------------- sorted path ----------------

// K1: per-block bucket histogram
__global__ __launch_bounds__(256) void hist_kernel(
        const float* __restrict__ pos, const float* __restrict__ nsx,
        const float* __restrict__ nsy, int* __restrict__ hist_part) {
    __shared__ int lh[NBUCK];
    int tid = threadIdx.x, b = blockIdx.x;
    if (tid < NBUCK) lh[tid] = 0;
    __syncthreads();
    int lo = b * CHUNK, hi = min(lo + CHUNK, NUM_PHYSICAL);
    for (int i = lo + tid; i < hi; i += 256) {
        float x_min, y_min, hx, hy;
        node_box(pos, nsx, nsy, i, x_min, y_min, hx, hy);
        atomicAdd(&lh[bucket_of(x_min, y_min, hx, hy)], 1);
    }
    __syncthreads();
    if (tid < NBUCK) hist_part[b * NBUCK + tid] = lh[tid];
}

// K2a: per bucket, exclusive prefix over the HB blocks' counts
__global__ __launch_bounds__(1024) void scan_blocks_kernel(
        const int* __restrict__ hist_part, int* __restrict__ off_part,
        int* __restrict__ buck_total) {
    __shared__ int sc[2][HB];
    int s = blockIdx.x, b = threadIdx.x;
    int v = hist_part[b * NBUCK + s];
    sc[0][b] = v;
    int src = 0;
    for (int off = 1; off < HB; off <<= 1) {
        __syncthreads();
        int x = sc[src][b];
        if (b >= off) x += sc[src][b - off];
        sc[src ^ 1][b] = x;
        src ^= 1;
    }
    __syncthreads();
    int incl = sc[src][b];
    off_part[b * NBUCK + s] = incl - v;   // exclusive prefix
    if (b == HB - 1) buck_total[s] = incl;
}

// K2b: exclusive prefix over the 256 bucket totals
__global__ __launch_bounds__(NBUCK) void scan_buckets_kernel(
        const int* __restrict__ buck_total, int* __restrict__ buck_start) {
    __shared__ int sc[2][NBUCK];
    int t = threadIdx.x;
    int v = buck_total[t];
    sc[0][t] = v;
    int src = 0;
    for (int off = 1; off < NBUCK; off <<= 1) {
        __syncthreads();
        int x = sc[src][t];
        if (t >= off) x += sc[src][t - off];
        sc[src ^ 1][t] = x;
        src ^= 1;
    }
    __syncthreads();
    int incl = sc[src][t];
    buck_start[t] = incl - v;
    if (t == NBUCK - 1) buck_start[NBUCK] = incl;
}

// K3: place compressed 16B payloads at sorted positions
__global__ __launch_bounds__(256) void place_kernel(
        const float* __restrict__ pos, const float* __restrict__ nsx,
        const float* __restrict__ nsy, const float* __restrict__ pw,
        const int* __restrict__ off_part, const int* __restrict__ buck_start,
        float4* __restrict__ pay) {
    __shared__ int lcur[NBUCK];
    int tid = threadIdx.x, b = blockIdx.x;
    if (tid < NBUCK) lcur[tid] = buck_start[tid] + off_part[b * NBUCK + tid];
    __syncthreads();
    int lo = b * CHUNK, hi = min(lo + CHUNK, NUM_PHYSICAL);
    for (int i = lo + tid; i < hi; i += 256) {
        float x_min, y_min, hx, hy;
        node_box(pos, nsx, nsy, i, x_min, y_min, hx, hy);
        float density = pw[i] / (4.0f * hx * hy);
        int bk = bucket_of(x_min, y_min, hx, hy);
        int p = atomicAdd(&lcur[bk], 1);
        pay[p] = make_float4(x_min, y_min, pack_hxy(hx, hy), density);
    }
}

// K4: shape-specialized scatter segment — exactly SX*SY ds_add slots per node
template <int SX, int SY>
__device__ __forceinline__ void scatter_seg(
        const float4* __restrict__ pay, int lo, int hi, int row0,
        unsigned int lds_base) {
    for (int p = lo + (int)threadIdx.x; p < hi; p += SCAT_THREADS) {
        float4 g = pay[p];
        float x_min = g.x, y_min = g.y, den = g.w;
        float hx, hy;
        unpack_hxy(g.z, hx, hy);
        float x_max = x_min + 2.0f * hx;
        float y_max = y_min + 2.0f * hy;
        int bxl = (int)floorf(x_min / BSX);
        int byl = (int)floorf(y_min / BSX);
        int L0 = byl - row0;
        // off-grid-in-y guard (rows are either all <0 or all >=NBY clipped)
        if ((unsigned)L0 > 7u) continue;

        float ox[SX], oy[SY];
        ox[0] = (float)(bxl + 1) * BSX - x_min;
        if (SX == 3) ox[1] = BSX;
        ox[SX - 1] = x_max - (float)(bxl + SX - 1) * BSX;
        oy[0] = (float)(byl + 1) * BSX - y_min;
        if (SY == 3) oy[1] = BSX;
        oy[SY - 1] = y_max - (float)(byl + SY - 1) * BSX;

        #pragma unroll
        for (int ry = 0; ry < SY; ++ry) {
            float w = oy[ry] * den;
            unsigned int rowoff = lds_base + 4u * (unsigned int)((L0 + ry) * NBX);
            #pragma unroll
            for (int rx = 0; rx < SX; ++rx) {
                int ix = bxl + rx;
                if ((unsigned)ix < (unsigned)NBX) {
                    unsigned int off = rowoff + 4u * (unsigned int)ix;
                    float v = ox[rx] * w;
                    asm volatile("ds_add_f32 %0, %1" :: "v"(off), "v"(v));
                }
            }
        }
    }
}

__global__ __launch_bounds__(SCAT_THREADS) void strip_scatter_kernel(
        const float4* __restrict__ pay, const int* __restrict__ buck_start,
        float* __restrict__ partial) {
    __shared__ float lacc[SCELLS];
    int tid = threadIdx.x;
    int s = blockIdx.x >> 3, r = blockIdx.x & (RREP - 1);
    for (int j = tid; j < SCELLS; j += SCAT_THREADS) lacc[j] = 0.0f;
    __syncthreads();
    unsigned int lds_base = (unsigned int)(uintptr_t)&lacc[0];
    int row0 = s * SROWS;

    #pragma unroll
    for (int sh = 0; sh < NSHAPE; ++sh) {
        int b0 = buck_start[s * NSHAPE + sh];
        int cnt = buck_start[s * NSHAPE + sh + 1] - b0;
        int lo = b0 + (int)(((long long)cnt * r) / RREP);
        int hi = b0 + (int)(((long long)cnt * (r + 1)) / RREP);
        // sh = shx*2 + shy; SX = 2+shx, SY = 2+shy
        if (sh == 0) scatter_seg<2, 2>(pay, lo, hi, row0, lds_base);
        if (sh == 1) scatter_seg<2, 3>(pay, lo, hi, row0, lds_base);
        if (sh == 2) scatter_seg<3, 2>(pay, lo, hi, row0, lds_base);
        if (sh == 3) scatter_seg<3, 3>(pay, lo, hi, row0, lds_base);
    }

    // drain all outstanding ds_add ops, then make them visible to the block
    asm volatile("s_waitcnt lgkmcnt(0)" ::: "memory");
    __syncthreads();
    float* dst = partial + (size_t)blockIdx.x * SCELLS;
    for (int j = tid; j < SCELLS; j += SCAT_THREADS) dst[j] = lacc[j];
}

// K5: gather replicas + y-halo, scale, clip; transpose via LDS so both the
// partial reads (contiguous x) and out writes ([x][y] layout) are coalesced
__global__ __launch_bounds__(1024) void final_kernel(
        const float* __restrict__ partial, float* __restrict__ out) {
    __shared__ float tile[32][33];
    int tx = threadIdx.x, ty = threadIdx.y;
    int x0 = blockIdx.x * 32, y0 = blockIdx.y * 32;
    int x = x0 + tx;          // x-bin (contiguous over lanes)
    int gy = y0 + ty;         // y-bin
    int s = gy >> 3, L = gy & 7;
    float sum = 0.0f;
    #pragma unroll
    for (int r = 0; r < RREP; ++r)
        sum += partial[(size_t)(s * RREP + r) * SCELLS + L * NBX + x];
    if (L < 2 && s > 0) {
        #pragma unroll
        for (int r = 0; r < RREP; ++r)
            sum += partial[(size_t)((s - 1) * RREP + r) * SCELLS + (L + SROWS) * NBX + x];
    }
    float u = sum / NORM_DIV;
    tile[ty][tx] = fminf(fmaxf(u, MIN_RATE), MAX_RATE);
    __syncthreads();
    out[(x0 + ty) * NBY + (y0 + tx)] = tile[tx][ty];
}

// ---------------- fallback path (proven) ----------------

__global__ void zero_acc_kernel(float* __restrict__ acc, int n) {
    int i = blockIdx.x * blockDim.x + threadIdx.x;
    if (i < n) acc[i] = 0.0f;
}

__global__ __launch_bounds__(256) void pin_scatter_kernel(
        const float* __restrict__ pos, const float* __restrict__ nsx,
        const float* __restrict__ nsy, const float* __restrict__ pw,
        float* __restrict__ acc) {
    int i = blockIdx.x * blockDim.x + threadIdx.x;
    if (i >= NUM_PHYSICAL) return;
    float x_min, y_min, hx, hy;
    node_box(pos, nsx, nsy, i, x_min, y_min, hx, hy);
    float x_max = x_min + 2.0f * hx, y_max = y_min + 2.0f * hy;
    float density = pw[i] / (4.0f * hx * hy);
    int bxl = (int)floorf(x_min / BSX);
    int byl = (int)floorf(y_min / BSX);
    #pragma unroll
    for (int kx = 0; kx < 3; ++kx) {
        int ix = bxl + kx;
        float bx_lo = (float)ix * BSX;
        float ox = fminf(x_max, bx_lo + BSX) - fmaxf(x_min, bx_lo);
        if (ix < 0 || ix >= NBX || !(ox > 0.0f)) continue;
        #pragma unroll
        for (int ky = 0; ky < 3; ++ky) {
            int iy = byl + ky;
            float by_lo = (float)iy * BSX;
            float oy = fminf(y_max, by_lo + BSX) - fmaxf(y_min, by_lo);
            if (iy >= 0 && iy < NBY && oy > 0.0f)
                atomicAdd(&acc[ix * NBY + iy], ox * oy * density);
        }
    }
}

__global__ void finalize_kernel(float* __restrict__ out, int n) {
    int i = blockIdx.x * blockDim.x + threadIdx.x;
    if (i < n) {
        float u = out[i] / NORM_DIV;
        out[i] = fminf(fmaxf(u, MIN_RATE), MAX_RATE);
    }
}

extern "C" void kernel_launch(void* const* d_in, const int* in_sizes, int n_in,
                              void* d_out, int out_size, void* d_ws, size_t ws_size,
                              hipStream_t stream) {
    const float* pos = (const float*)d_in[0];
    const float* nsx = (const float*)d_in[1];
    const float* nsy = (const float*)d_in[2];
    const float* pw  = (const float*)d_in[3];
    float* out = (float*)d_out;

    // workspace layout (bytes)
    const size_t OFF_PAY  = 0;                                    // 32,000,000
    const size_t OFF_HIST = 32000000;                             // HB*NBUCK*4 = 1,048,576
    const size_t OFF_OFFP = OFF_HIST + (size_t)HB * NBUCK * 4;    // 1,048,576
    const size_t OFF_BTOT = OFF_OFFP + (size_t)HB * NBUCK * 4;    // 1,024
    const size_t OFF_BSTR = OFF_BTOT + NBUCK * 4;                 // 1,028
    const size_t OFF_PART = (OFF_BSTR + (NBUCK + 1) * 4 + 255) & ~(size_t)255;
    const size_t WS_NEEDED = OFF_PART + (size_t)SCAT_BLOCKS * SCELLS * 4; // ~44.6 MB

    if (ws_size >= WS_NEEDED) {
        char* w = (char*)d_ws;
        float4* pay      = (float4*)(w + OFF_PAY);
        int*    hist_prt = (int*)   (w + OFF_HIST);
        int*    off_part = (int*)   (w + OFF_OFFP);
        int*    buck_tt  = (int*)   (w + OFF_BTOT);
        int*    buck_st  = (int*)   (w + OFF_BSTR);
        float*  partial  = (float*) (w + OFF_PART);

        hist_kernel<<<HB, 256, 0, stream>>>(pos, nsx, nsy, hist_prt);
        scan_blocks_kernel<<<NBUCK, HB, 0, stream>>>(hist_prt, off_part, buck_tt);
        scan_buckets_kernel<<<1, NBUCK, 0, stream>>>(buck_tt, buck_st);
        place_kernel<<<HB, 256, 0, stream>>>(pos, nsx, nsy, pw,
                                             off_part, buck_st, pay);
        strip_scatter_kernel<<<SCAT_BLOCKS, SCAT_THREADS, 0, stream>>>(
            pay, buck_st, partial);
        final_kernel<<<dim3(NBX / 32, NBY / 32), dim3(32, 32), 0, stream>>>(partial, out);
    } else {
        zero_acc_kernel<<<(NBINS + 255) / 256, 256, 0, stream>>>(out, NBINS);
        pin_scatter_kernel<<<(NUM_PHYSICAL + 255) / 256, 256, 0, stream>>>(
            pos, nsx, nsy, pw, out);
        finalize_kernel<<<(NBINS + 255) / 256, 256, 0, stream>>>(out, NBINS);
    }
}

// Round 9
// 45.663 us; speedup vs baseline: 2.4422x; 2.4422x over previous
//
#include <hip/hip_runtime.h>
#include <hip/hip_fp16.h>

// Problem constants (must match reference)
#define NUM_PHYSICAL 2000000
#define NUM_NODES    2500000   // 2,000,000 physical + 500,000 filler
#define NBX 512
#define NBY 512
#define NBINS (NBX * NBY)

// BSX = BSY = 1000/512 = 1.953125 (exact in binary)
#define BSX 1.953125f
#define HALF_STRETCH ((float)(0.5 * 1.953125 * 1.4142135623730951))
// BSX*BSY*UNIT_PIN_CAPACITY = 61.03515625 (exact); x 65536 = 4,000,000 exactly
#define INV_Q_NORM (1.0f / 4000000.0f)
#define NORM_DIV 61.03515625f
#define MAX_RATE 2.5f
#define MIN_RATE 0.4f   // 1/2.5 exactly

// Strip bucketing: 64 strips of 8 y-rows each.
#define NSTRIP 64
#define SROWS 8                  // rows per strip
#define LROWS 10                 // 8 + 2 y-halo (node spans <=3 rows)
#define SCELLS (NBX * LROWS)     // 5120 u32 = 20 KB LDS, col-major [col][row]
#define RREP 8                   // scatter replicas per strip
#define SCAT_BLOCKS (NSTRIP * RREP)
#define SCAT_THREADS 1024
#define HB 1024                  // blocks for hist/placement
#define CHUNK ((NUM_PHYSICAL + HB - 1) / HB)   // 1954

__device__ __forceinline__ int strip_of(float y_min) {
    int byl = (int)floorf(y_min / BSX);
    return (min(max(byl, 0), NBY - 1)) >> 3;
}

__device__ __forceinline__ void node_box(const float* __restrict__ pos,
                                         const float* __restrict__ nsx,
                                         const float* __restrict__ nsy, int i,
                                         float& x_min, float& y_min,
                                         float& hx, float& hy) {
    float sx = nsx[i], sy = nsy[i];
    hx = 0.5f * fmaxf(sx, 2.0f * HALF_STRETCH);
    hy = 0.5f * fmaxf(sy, 2.0f * HALF_STRETCH);
    x_min = (pos[i]             + 0.5f * sx) - hx;
    y_min = (pos[NUM_NODES + i] + 0.5f * sy) - hy;
}

__device__ __forceinline__ float pack_hxy(float hx, float hy) {
    unsigned int u = ((unsigned int)__half_as_ushort(__float2half_rn(hy)) << 16)
                   |  (unsigned int)__half_as_ushort(__float2half_rn(hx));
    return __uint_as_float(u);
}
__device__ __forceinline__ void unpack_hxy(float p, float& hx, float& hy) {
    unsigned int u = __float_as_uint(p);
    hx = __half2float(__ushort_as_half((unsigned short)(u & 0xffffu)));
    hy = __half2float(__ushort_as_half((unsigned short)(u >> 16)));
}

// ---------------- sorted-strip path ----------------

// K1: per-block strip histogram (y data only)
__global__ __launch_bounds__(256) void hist_kernel(
        const float* __restrict__ pos, const float* __restrict__ nsy,
        int* __restrict__ hist_part) {
    __shared__ int lh[NSTRIP];
    int tid = threadIdx.x, b = blockIdx.x;
    if (tid < NSTRIP) lh[tid] = 0;
    __syncthreads();
    int lo = b * CHUNK, hi = min(lo + CHUNK, NUM_PHYSICAL);
    for (int i = lo + tid; i < hi; i += 256) {
        float sy = nsy[i];
        float hy = 0.5f * fmaxf(sy, 2.0f * HALF_STRETCH);
        float y_min = (pos[NUM_NODES + i] + 0.5f * sy) - hy;
        atomicAdd(&lh[strip_of(y_min)], 1);
    }
    __syncthreads();
    if (tid < NSTRIP) hist_part[b * NSTRIP + tid] = lh[tid];
}

// K2a: per strip, exclusive prefix over the HB blocks' counts
__global__ __launch_bounds__(1024) void scan_blocks_kernel(
        const int* __restrict__ hist_part, int* __restrict__ off_part,
        int* __restrict__ strip_total) {
    __shared__ int sc[2][HB];
    int s = blockIdx.x, b = threadIdx.x;
    int v = hist_part[b * NSTRIP + s];
    sc[0][b] = v;
    int src = 0;
    for (int off = 1; off < HB; off <<= 1) {
        __syncthreads();
        int x = sc[src][b];
        if (b >= off) x += sc[src][b - off];
        sc[src ^ 1][b] = x;
        src ^= 1;
    }
    __syncthreads();
    int incl = sc[src][b];
    off_part[b * NSTRIP + s] = incl - v;   // exclusive prefix
    if (b == HB - 1) strip_total[s] = incl;
}

// K2b: exclusive prefix over the 64 strip totals
__global__ __launch_bounds__(64) void scan_strips_kernel(
        const int* __restrict__ strip_total, int* __restrict__ strip_start) {
    __shared__ int sc[2][NSTRIP];
    int t = threadIdx.x;
    int v = strip_total[t];
    sc[0][t] = v;
    int src = 0;
    for (int off = 1; off < NSTRIP; off <<= 1) {
        __syncthreads();
        int x = sc[src][t];
        if (t >= off) x += sc[src][t - off];
        sc[src ^ 1][t] = x;
        src ^= 1;
    }
    __syncthreads();
    int incl = sc[src][t];
    strip_start[t] = incl - v;
    if (t == NSTRIP - 1) strip_start[NSTRIP] = incl;
}

// K3: place compressed 16B payloads at sorted positions (deterministic slots)
__global__ __launch_bounds__(256) void place_kernel(
        const float* __restrict__ pos, const float* __restrict__ nsx,
        const float* __restrict__ nsy, const float* __restrict__ pw,
        const int* __restrict__ off_part, const int* __restrict__ strip_start,
        float4* __restrict__ pay) {
    __shared__ int lcur[NSTRIP];
    int tid = threadIdx.x, b = blockIdx.x;
    if (tid < NSTRIP) lcur[tid] = strip_start[tid] + off_part[b * NSTRIP + tid];
    __syncthreads();
    int lo = b * CHUNK, hi = min(lo + CHUNK, NUM_PHYSICAL);
    for (int i = lo + tid; i < hi; i += 256) {
        float x_min, y_min, hx, hy;
        node_box(pos, nsx, nsy, i, x_min, y_min, hx, hy);
        float density = pw[i] / (4.0f * hx * hy);
        int s = strip_of(y_min);
        int p = atomicAdd(&lcur[s], 1);
        pay[p] = make_float4(x_min, y_min, pack_hxy(hx, hy), density);
    }
}

// K4: strip scatter — fixed-point u32 accumulator, col-major [col][10 rows],
// each column's 2-3 consecutive-row contributions fused into 1-2 ds_add_u64.
__global__ __launch_bounds__(SCAT_THREADS) void strip_scatter_kernel(
        const float4* __restrict__ pay, const int* __restrict__ strip_start,
        unsigned int* __restrict__ partial) {
    __shared__ unsigned int lacc[SCELLS];
    int tid = threadIdx.x;
    int s = blockIdx.x >> 3, r = blockIdx.x & (RREP - 1);
    for (int j = tid; j < SCELLS; j += SCAT_THREADS) lacc[j] = 0u;
    __syncthreads();
    unsigned int lds_base = (unsigned int)(uintptr_t)&lacc[0];
    int lo0 = strip_start[s], count = strip_start[s + 1] - lo0;
    int lo = lo0 + (int)(((long long)count * r) / RREP);
    int hi = lo0 + (int)(((long long)count * (r + 1)) / RREP);
    int row0 = s * SROWS;

    for (int p = lo + tid; p < hi; p += SCAT_THREADS) {
        float4 g = pay[p];
        float x_min = g.x, y_min = g.y, den = g.w;
        float hx, hy;
        unpack_hxy(g.z, hx, hy);
        float x_max = x_min + 2.0f * hx;
        float y_max = y_min + 2.0f * hy;
        int bxl = (int)floorf(x_min / BSX);
        int byl = (int)floorf(y_min / BSX);
        int L0 = byl - row0;
        if ((unsigned)L0 > 7u) continue;   // memory-safety guard

        // row overlaps (oy0, oy1 always > 0 for interior nodes; oy2 may be <=0)
        float oy0 = (float)(byl + 1) * BSX - y_min;
        float oy1 = fminf(y_max - (float)(byl + 1) * BSX, BSX);
        float oy2 = y_max - (float)(byl + 2) * BSX;
        float qs = den * 65536.0f;
        float f0 = oy0 * qs;
        float f1 = oy1 * qs;
        float f2 = fmaxf(oy2, 0.0f) * qs;
        // col overlaps
        float ox0 = (float)(bxl + 1) * BSX - x_min;
        float ox1 = fminf(x_max - (float)(bxl + 1) * BSX, BSX);
        float ox2 = x_max - (float)(bxl + 2) * BSX;

        bool odd = (L0 & 1) != 0;
        unsigned int base0 = lds_base + (unsigned int)((L0 >> 1) * 8);

        #define DO_COL(ox_, ix_) {                                             \
            unsigned int u0 = (unsigned int)((ox_) * f0 + 0.5f);               \
            unsigned int u1 = (unsigned int)((ox_) * f1 + 0.5f);               \
            unsigned int u2 = (unsigned int)((ox_) * f2 + 0.5f);               \
            unsigned long long A, B;                                           \
            if (!odd) { A = (unsigned long long)u0 |                           \
                            ((unsigned long long)u1 << 32);                    \
                        B = (unsigned long long)u2; }                          \
            else      { A = ((unsigned long long)u0) << 32;                    \
                        B = (unsigned long long)u1 |                           \
                            ((unsigned long long)u2 << 32); }                  \
            unsigned int offA = base0 + (unsigned int)(ix_) * 40u;             \
            asm volatile("ds_add_u64 %0, %1" :: "v"(offA), "v"(A));            \
            if (B) asm volatile("ds_add_u64 %0, %1" :: "v"(offA + 8u), "v"(B)); }

        if ((unsigned)bxl < (unsigned)NBX)       DO_COL(ox0, bxl);
        if ((unsigned)(bxl + 1) < (unsigned)NBX) DO_COL(ox1, bxl + 1);
        if (ox2 > 0.0f && (unsigned)(bxl + 2) < (unsigned)NBX) DO_COL(ox2, bxl + 2);
        #undef DO_COL
    }

    // drain all outstanding ds_add ops, then make them visible to the block
    asm volatile("s_waitcnt lgkmcnt(0)" ::: "memory");
    __syncthreads();
    // transpose to row-major [row][col] on writeback so K5 reads coalesced
    unsigned int* dst = partial + (size_t)blockIdx.x * SCELLS;
    for (int j = tid; j < SCELLS; j += SCAT_THREADS) {
        int row = j >> 9, col = j & (NBX - 1);
        dst[j] = lacc[col * LROWS + row];
    }
}

// K5: gather replicas + y-halo (u32 exact sums), dequant, clip; transpose via
// LDS so both partial reads (contiguous x) and out writes ([x][y]) coalesce
__global__ __launch_bounds__(1024) void final_kernel(
        const unsigned int* __restrict__ partial, float* __restrict__ out) {
    __shared__ float tile[32][33];
    int tx = threadIdx.x, ty = threadIdx.y;
    int x0 = blockIdx.x * 32, y0 = blockIdx.y * 32;
    int x = x0 + tx;          // x-bin (contiguous over lanes)
    int gy = y0 + ty;         // y-bin
    int s = gy >> 3, L = gy & 7;
    unsigned int sum = 0u;
    #pragma unroll
    for (int r = 0; r < RREP; ++r)
        sum += partial[(size_t)(s * RREP + r) * SCELLS + L * NBX + x];
    if (L < 2 && s > 0) {
        #pragma unroll
        for (int r = 0; r < RREP; ++r)
            sum += partial[(size_t)((s - 1) * RREP + r) * SCELLS + (L + SROWS) * NBX + x];
    }
    float u = (float)sum * INV_Q_NORM;
    tile[ty][tx] = fminf(fmaxf(u, MIN_RATE), MAX_RATE);
    __syncthreads();
    out[(x0 + ty) * NBY + (y0 + tx)] = tile[tx][ty];
}

// ---------------- fallback path (proven) ----------------

__global__ void zero_acc_kernel(float* __restrict__ acc, int n) {
    int i = blockIdx.x * blockDim.x + threadIdx.x;
    if (i < n) acc[i] = 0.0f;
}

__global__ __launch_bounds__(256) void pin_scatter_kernel(
        const float* __restrict__ pos, const float* __restrict__ nsx,
        const float* __restrict__ nsy, const float* __restrict__ pw,
        float* __restrict__ acc) {
    int i = blockIdx.x * blockDim.x + threadIdx.x;
    if (i >= NUM_PHYSICAL) return;
    float x_min, y_min, hx, hy;
    node_box(pos, nsx, nsy, i, x_min, y_min, hx, hy);
    float x_max = x_min + 2.0f * hx, y_max = y_min + 2.0f * hy;
    float density = pw[i] / (4.0f * hx * hy);
    int bxl = (int)floorf(x_min / BSX);
    int byl = (int)floorf(y_min / BSX);
    #pragma unroll
    for (int kx = 0; kx < 3; ++kx) {
        int ix = bxl + kx;
        float bx_lo = (float)ix * BSX;
        float ox = fminf(x_max, bx_lo + BSX) - fmaxf(x_min, bx_lo);
        if (ix < 0 || ix >= NBX || !(ox > 0.0f)) continue;
        #pragma unroll
        for (int ky = 0; ky < 3; ++ky) {
            int iy = byl + ky;
            float by_lo = (float)iy * BSX;
            float oy = fminf(y_max, by_lo + BSX) - fmaxf(y_min, by_lo);
            if (iy >= 0 && iy < NBY && oy > 0.0f)
                atomicAdd(&acc[ix * NBY + iy], ox * oy * density);
        }
    }
}

__global__ void finalize_kernel(float* __restrict__ out, int n) {
    int i = blockIdx.x * blockDim.x + threadIdx.x;
    if (i < n) {
        float u = out[i] / NORM_DIV;
        out[i] = fminf(fmaxf(u, MIN_RATE), MAX_RATE);
    }
}

extern "C" void kernel_launch(void* const* d_in, const int* in_sizes, int n_in,
                              void* d_out, int out_size, void* d_ws, size_t ws_size,
                              hipStream_t stream) {
    const float* pos = (const float*)d_in[0];
    const float* nsx = (const float*)d_in[1];
    const float* nsy = (const float*)d_in[2];
    const float* pw  = (const float*)d_in[3];
    float* out = (float*)d_out;

    // workspace layout (bytes)
    const size_t OFF_PAY  = 0;                                   // 2M float4 = 32,000,000
    const size_t OFF_HIST = 32000000;                            // HB*NSTRIP int = 262,144
    const size_t OFF_OFFP = OFF_HIST + (size_t)HB * NSTRIP * 4;  // 262,144
    const size_t OFF_TTOT = OFF_OFFP + (size_t)HB * NSTRIP * 4;  // 256
    const size_t OFF_TSTR = OFF_TTOT + NSTRIP * 4;               // 260
    const size_t OFF_PART = (OFF_TSTR + (NSTRIP + 1) * 4 + 255) & ~(size_t)255;
    const size_t WS_NEEDED = OFF_PART + (size_t)SCAT_BLOCKS * SCELLS * 4; // ~43.0 MB

    if (ws_size >= WS_NEEDED) {
        char* w = (char*)d_ws;
        float4*       pay      = (float4*)      (w + OFF_PAY);
        int*          hist_prt = (int*)         (w + OFF_HIST);
        int*          off_part = (int*)         (w + OFF_OFFP);
        int*          strip_tt = (int*)         (w + OFF_TTOT);
        int*          strip_st = (int*)         (w + OFF_TSTR);
        unsigned int* partial  = (unsigned int*)(w + OFF_PART);

        hist_kernel<<<HB, 256, 0, stream>>>(pos, nsy, hist_prt);
        scan_blocks_kernel<<<NSTRIP, HB, 0, stream>>>(hist_prt, off_part, strip_tt);
        scan_strips_kernel<<<1, NSTRIP, 0, stream>>>(strip_tt, strip_st);
        place_kernel<<<HB, 256, 0, stream>>>(pos, nsx, nsy, pw,
                                             off_part, strip_st, pay);
        strip_scatter_kernel<<<SCAT_BLOCKS, SCAT_THREADS, 0, stream>>>(
            pay, strip_st, partial);
        final_kernel<<<dim3(NBX / 32, NBY / 32), dim3(32, 32), 0, stream>>>(partial, out);
    } else {
        zero_acc_kernel<<<(NBINS + 255) / 256, 256, 0, stream>>>(out, NBINS);
        pin_scatter_kernel<<<(NUM_PHYSICAL + 255) / 256, 256, 0, stream>>>(
            pos, nsx, nsy, pw, out);
        finalize_kernel<<<(NBINS + 255) / 256, 256, 0, stream>>>(out, NBINS);
    }
}